// Round 1
// baseline (117.885 us; speedup 1.0000x reference)
//
#include <hip/hip_runtime.h>
#include <hip/hip_bf16.h>

// out[b][n] = x[b][n] * |W[n][n]|   (BATCH=65536, N=1024, f32)
// Memory-bound elementwise column scale. float4 everywhere.

#define N_COLS 1024
#define BLOCK 256   // 256 threads * 4 floats = one full row per block-iteration

__global__ __launch_bounds__(BLOCK) void diag_scale_kernel(
    const float* __restrict__ x,
    const float* __restrict__ W,
    float* __restrict__ out,
    int rows)
{
    const int t = threadIdx.x;          // 0..255
    const int c0 = t * 4;               // first of this thread's 4 columns

    // Diagonal values: W[c][c] at flat index c*(N+1) = c*1025. Loaded once,
    // scattered but tiny (1024 lines total) -> L2-resident after first touch.
    const float w0 = fabsf(W[(size_t)(c0 + 0) * (N_COLS + 1)]);
    const float w1 = fabsf(W[(size_t)(c0 + 1) * (N_COLS + 1)]);
    const float w2 = fabsf(W[(size_t)(c0 + 2) * (N_COLS + 1)]);
    const float w3 = fabsf(W[(size_t)(c0 + 3) * (N_COLS + 1)]);

    const float4* __restrict__ xv = reinterpret_cast<const float4*>(x);
    float4* __restrict__ ov = reinterpret_cast<float4*>(out);
    const int row_f4 = N_COLS / 4;      // 256 float4 per row

    for (int row = blockIdx.x; row < rows; row += gridDim.x) {
        const size_t idx = (size_t)row * row_f4 + t;
        float4 v = xv[idx];
        v.x *= w0;
        v.y *= w1;
        v.z *= w2;
        v.w *= w3;
        ov[idx] = v;
    }
}

extern "C" void kernel_launch(void* const* d_in, const int* in_sizes, int n_in,
                              void* d_out, int out_size, void* d_ws, size_t ws_size,
                              hipStream_t stream)
{
    const float* x = (const float*)d_in[0];   // [BATCH, N]
    const float* W = (const float*)d_in[1];   // [N, N]
    float* out = (float*)d_out;               // [BATCH, N]

    const int rows = in_sizes[0] / N_COLS;    // 65536

    // ~2048 blocks: 256 CUs * 8 blocks/CU; grid-stride covers the rest.
    const int grid = 2048;
    diag_scale_kernel<<<grid, BLOCK, 0, stream>>>(x, W, out, rows);
}